// Round 11
// baseline (15002.071 us; speedup 1.0000x reference)
//
#include <hip/hip_runtime.h>

#define B_ 128
#define T_ 200
#define INF_ 175
#define INFP_ 192
#define H_ 1024
#define G4_ 4096
#define OUTF_ 175
#define BH3_ (3 * B_ * H_)
#define NCELL 192
#define NDEC 22
#define NWORK (NCELL + NDEC)   // 214 worker blocks
#define NBLK (NWORK + 1)       // + 1 master block
#define SP 16                  // sync padding: 1 flag per 64B line

typedef __bf16 bf16x8 __attribute__((ext_vector_type(8)));
typedef float f32x4 __attribute__((ext_vector_type(4)));

// ---- persistent device state ----
__device__ __attribute__((aligned(16))) __bf16 g_Wih1p[G4_ * INFP_];
__device__ __attribute__((aligned(16))) __bf16 g_Whh1[G4_ * H_];
__device__ __attribute__((aligned(16))) __bf16 g_Wih2[G4_ * H_];
__device__ __attribute__((aligned(16))) __bf16 g_Whh2[G4_ * H_];
__device__ __attribute__((aligned(16))) __bf16 g_Wih3[G4_ * H_];
__device__ __attribute__((aligned(16))) __bf16 g_Whh3[G4_ * H_];
__device__ __attribute__((aligned(16))) __bf16 g_Wdec[OUTF_ * H_];
__device__ float g_bsum[3 * G4_];
__device__ float g_bdec[OUTF_];
__device__ __attribute__((aligned(16))) __bf16 g_h[2][BH3_];
__device__ __attribute__((aligned(16))) __bf16 g_infp[B_ * INFP_];
__device__ int g_isf32;
// ---- sync state: accessed ONLY via atomic RMWs (coherence-point execution).
// Padded to one word per 64B line. Monotonic within a launch; reset by prep_k.
__device__ int g_flags[256 * SP];   // per-worker arrival
__device__ int g_dflags[32 * SP];   // per-dec-block infp-ready
__device__ int g_gen8[8 * SP];      // 8 broadcast generation words
__device__ int g_iready8[8 * SP];   // infp-ready step, replicated 8x

__device__ __forceinline__ f32x4 mfma_bf16(bf16x8 a, bf16x8 b, f32x4 c) {
    return __builtin_amdgcn_mfma_f32_16x16x32_bf16(a, b, c, 0, 0, 0);
}
__device__ __forceinline__ bf16x8 ld8(const __bf16* p) {
    return *reinterpret_cast<const bf16x8*>(p);
}
__device__ __forceinline__ float sigm(float x) { return 1.f / (1.f + expf(-x)); }
__device__ __forceinline__ float rdf(const void* p, long i, int f32) {
    return f32 ? ((const float*)p)[i] : (float)((const __bf16*)p)[i];
}
__device__ __forceinline__ unsigned short bf2u(__bf16 v) {
    union { __bf16 b; unsigned short u; } c; c.b = v; return c.u;
}

// RMW-poll: fetch_max(addr,0) returns the CURRENT value from the L3 coherence
// point every poll (never served by a stale local line; max(x,0) is not in
// LLVM's idempotent-RMW list so it stays a real atomic). One ACQUIRE at exit
// invalidates L1/L2 so subsequent DATA loads are fresh. Bounded (hang-proof).
__device__ __forceinline__ void spin_rmw(int* addr, int target, int iters) {
    for (int it = 0; it < iters; ++it) {
        if (__hip_atomic_fetch_max(addr, 0, __ATOMIC_RELAXED, __HIP_MEMORY_SCOPE_AGENT) >= target)
            break;
        __builtin_amdgcn_s_sleep(1);
    }
    (void)__hip_atomic_load(addr, __ATOMIC_ACQUIRE, __HIP_MEMORY_SCOPE_AGENT);
}

// ---- dtype probe ----
__global__ void detect_k(const unsigned int* __restrict__ xw) {
    __shared__ int cnt;
    if (threadIdx.x == 0) cnt = 0;
    __syncthreads();
    unsigned int w = xw[threadIdx.x];
    int e = (w >> 7) & 0xFF;
    if (e >= 140) atomicAdd(&cnt, 1);
    __syncthreads();
    if (threadIdx.x == 0) g_isf32 = (cnt >= 16) ? 1 : 0;
}

// ---- prep: weights->bf16, bias sums, zero state, infp(0), reset ALL sync ----
__global__ void prep_k(const void* Wih1, const void* Whh1, const void* Wih2,
                       const void* Whh2, const void* Wih3, const void* Whh3,
                       const void* Wdec, const void* bih1, const void* bhh1,
                       const void* bih2, const void* bhh2, const void* bih3,
                       const void* bhh3, const void* bdec, const void* xseq) {
    const int f = g_isf32;
    const int idx = blockIdx.x * 256 + threadIdx.x;
    const int stride = gridDim.x * 256;
    if (idx < 256 * SP) g_flags[idx] = 0;
    if (idx < 32 * SP) g_dflags[idx] = 0;
    if (idx < 8 * SP) { g_gen8[idx] = 0; g_iready8[idx] = 0; }
    for (int i = idx; i < G4_ * INFP_; i += stride) {
        int n = i / INFP_, k = i - n * INFP_;
        g_Wih1p[i] = (k < INF_) ? (__bf16)rdf(Wih1, (long)n * INF_ + k, f) : (__bf16)0.f;
    }
    for (int i = idx; i < G4_ * H_; i += stride) {
        g_Whh1[i] = (__bf16)rdf(Whh1, i, f);
        g_Wih2[i] = (__bf16)rdf(Wih2, i, f);
        g_Whh2[i] = (__bf16)rdf(Whh2, i, f);
        g_Wih3[i] = (__bf16)rdf(Wih3, i, f);
        g_Whh3[i] = (__bf16)rdf(Whh3, i, f);
    }
    for (int i = idx; i < OUTF_ * H_; i += stride) g_Wdec[i] = (__bf16)rdf(Wdec, i, f);
    for (int i = idx; i < G4_; i += stride) {
        g_bsum[i]           = rdf(bih1, i, f) + rdf(bhh1, i, f);
        g_bsum[G4_ + i]     = rdf(bih2, i, f) + rdf(bhh2, i, f);
        g_bsum[2 * G4_ + i] = rdf(bih3, i, f) + rdf(bhh3, i, f);
    }
    for (int i = idx; i < OUTF_; i += stride) g_bdec[i] = rdf(bdec, i, f);
    for (int i = idx; i < 2 * BH3_; i += stride) (&g_h[0][0])[i] = (__bf16)0.f;
    for (int i = idx; i < B_ * INFP_; i += stride) {
        int b = i / INFP_, k = i - b * INFP_;
        g_infp[i] = (k < INF_) ? (__bf16)rdf(xseq, (long)b * (T_ * INF_) + k, f) : (__bf16)0.f;
    }
}

// ---- worker barrier: RMW arrival (coherence-point visible immediately),
// RMW poll of the group's gen word, one acquire at exit.
__device__ __forceinline__ void gridbar_w(int bid, int grp, int target) {
    __syncthreads();   // drains each wave's vmcnt (NT stores at L3) pre-arrival
    if (threadIdx.x == 0) {
        __threadfence();  // cheap: NT data path leaves little dirty in L2
        __hip_atomic_fetch_max(&g_flags[bid * SP], target, __ATOMIC_RELAXED, __HIP_MEMORY_SCOPE_AGENT);
        spin_rmw(&g_gen8[grp * SP], target, 4000);
    }
    __syncthreads();
}

// depth-2 register-pipelined GEMM over NCH k-chunks for m-frags [BASE,BASE+4)
template <int NCH, int BASE>
__device__ __forceinline__ void gemm_half(const __bf16* const (&ap)[8],
                                          const bf16x8 (&wreg)[32],
                                          f32x4 (&acc)[8]) {
    bf16x8 a0[4], a1[4];
#pragma unroll
    for (int mf = 0; mf < 4; ++mf) a0[mf] = ld8(ap[BASE + mf]);
    if (NCH > 1) {
#pragma unroll
        for (int mf = 0; mf < 4; ++mf) a1[mf] = ld8(ap[BASE + mf] + 32);
    }
#pragma unroll
    for (int c = 0; c < NCH; c += 2) {
#pragma unroll
        for (int mf = 0; mf < 4; ++mf)
            acc[BASE + mf] = mfma_bf16(a0[mf], wreg[c], acc[BASE + mf]);
        if (c + 2 < NCH) {
#pragma unroll
            for (int mf = 0; mf < 4; ++mf) a0[mf] = ld8(ap[BASE + mf] + (c + 2) * 32);
        }
        if (c + 1 < NCH) {
#pragma unroll
            for (int mf = 0; mf < 4; ++mf)
                acc[BASE + mf] = mfma_bf16(a1[mf], wreg[c + 1], acc[BASE + mf]);
            if (c + 3 < NCH) {
#pragma unroll
                for (int mf = 0; mf < 4; ++mf) a1[mf] = ld8(ap[BASE + mf] + (c + 3) * 32);
            }
        }
    }
}

// ---- persistent kernel ----
__global__ __launch_bounds__(512, 1) void persist_k(const void* __restrict__ xseq,
                                                    void* __restrict__ dout) {
    __shared__ float s_acc[B_ * 4 * 16];  // 32KB
    __shared__ float s_c[B_ * 16];        // 8KB
    __shared__ int s_nf, s_nd;
    const int bid = blockIdx.x;
    const int grp = bid & 7;
    const int tid = threadIdx.x;
    const int lane = tid & 63;
    const int wid = tid >> 6;
    const int rlo = lane & 15, khi = lane >> 4;
    const int f32o = g_isf32;

    if (bid < NCELL) {
        // ================= CELL BLOCK =================
        const int L = bid >> 6;
        const int hc0 = (bid & 63) << 4;
        const int op = wid >> 2;         // 0: x-GEMM, 1: recurrent GEMM
        const int g = wid & 3;           // gate
        const float* bs = g_bsum + L * G4_;

        const __bf16* Bm; int K;
        if (op == 0) {
            if (L == 0) { Bm = g_Wih1p; K = INFP_; }
            else        { Bm = (L == 1) ? g_Wih2 : g_Wih3; K = H_; }
        } else {
            Bm = (L == 0) ? g_Whh1 : (L == 1) ? g_Whh2 : g_Whh3; K = H_;
        }
        const __bf16* wp = Bm + (long)(g * H_ + hc0 + rlo) * K + khi * 8;
        bf16x8 wreg[32];
        if (K == INFP_) {
#pragma unroll
            for (int c = 0; c < 6; ++c) wreg[c] = ld8(wp + c * 32);
        } else {
#pragma unroll
            for (int c = 0; c < 32; ++c) wreg[c] = ld8(wp + c * 32);
        }

        for (int i = tid; i < B_ * 16; i += 512) s_c[i] = 0.f;

        for (int p = 0; p < T_; ++p) {
            const __bf16* hin = g_h[p & 1];
            const __bf16* Ap; int sA;
            if (op == 0) {
                if (L == 0) { Ap = g_infp; sA = INFP_; }
                else        { Ap = hin + (L - 1) * B_ * H_; sA = H_; }
            } else { Ap = hin + L * B_ * H_; sA = H_; }

            // L0 x-waves wait for this step's in_frame readiness; the acquire
            // inside spin_rmw invalidates stale infp lines before the loads.
            if (L == 0 && op == 0 && p > 0) {
                if (lane == 0) spin_rmw(&g_iready8[grp * SP], p, 3000);
            }

            const __bf16* ap[8];
#pragma unroll
            for (int mf = 0; mf < 8; ++mf)
                ap[mf] = Ap + (mf * 16 + rlo) * sA + khi * 8;

            f32x4 acc[8] = {};
            if (K == INFP_) {
                gemm_half<6, 0>(ap, wreg, acc);
                gemm_half<6, 4>(ap, wreg, acc);
            } else {
                gemm_half<32, 0>(ap, wreg, acc);
                gemm_half<32, 4>(ap, wreg, acc);
            }

            if (op == 1) {
#pragma unroll
                for (int mf = 0; mf < 8; ++mf)
#pragma unroll
                    for (int j = 0; j < 4; ++j) {
                        int r = mf * 16 + khi * 4 + j;
                        s_acc[(r * 4 + g) * 16 + rlo] = acc[mf][j];
                    }
            }
            __syncthreads();
            if (op == 0) {
#pragma unroll
                for (int mf = 0; mf < 8; ++mf)
#pragma unroll
                    for (int j = 0; j < 4; ++j) {
                        int r = mf * 16 + khi * 4 + j;
                        s_acc[(r * 4 + g) * 16 + rlo] += acc[mf][j];
                    }
            }
            __syncthreads();

            // epilogue: 8 waves x 16 rows, 4 cols/lane; h out = NT store (to L3)
            {
                const int r = wid * 16 + rlo;
                const int hq = khi;
                f32x4 ga = *(const f32x4*)&s_acc[(r * 4 + 0) * 16 + hq * 4];
                f32x4 gf = *(const f32x4*)&s_acc[(r * 4 + 1) * 16 + hq * 4];
                f32x4 gg = *(const f32x4*)&s_acc[(r * 4 + 2) * 16 + hq * 4];
                f32x4 go = *(const f32x4*)&s_acc[(r * 4 + 3) * 16 + hq * 4];
                f32x4 cv = *(const f32x4*)&s_c[r * 16 + hq * 4];
                unsigned long long hbits;
                unsigned short* hp = (unsigned short*)&hbits;
#pragma unroll
                for (int e = 0; e < 4; ++e) {
                    int col = hc0 + hq * 4 + e;
                    float gi_ = ga[e] + bs[0 * H_ + col];
                    float gf_ = gf[e] + bs[1 * H_ + col];
                    float gg_ = gg[e] + bs[2 * H_ + col];
                    float go_ = go[e] + bs[3 * H_ + col];
                    float cn = sigm(gf_) * cv[e] + sigm(gi_) * tanhf(gg_);
                    cv[e] = cn;
                    hp[e] = bf2u((__bf16)(sigm(go_) * tanhf(cn)));
                }
                *(f32x4*)&s_c[r * 16 + hq * 4] = cv;
                __bf16* hdst = g_h[(p + 1) & 1] + L * B_ * H_ + r * H_ + hc0 + hq * 4;
                __builtin_nontemporal_store(hbits, (unsigned long long*)hdst);
            }
            gridbar_w(bid, grp, p + 1);
        }
    } else if (bid < NWORK) {
        // ================= DEC BLOCK =================
        const int db = bid - NCELL;
        const int ntile = db % 11, mh = db / 11;
        const int kk = wid >> 2;
        const int mw = wid & 3;
        const int col = ntile * 16 + rlo;
        const int colc = (col < OUTF_) ? col : (OUTF_ - 1);

        auto decwork = [&](int t, bool winf) {
            const bool gt = (((t + 1) % 10) < 5);
            // gt fast-path: infp(t+1) from xseq, independent of this GEMM
            if (winf && gt) {
                if (kk == 0 && col < OUTF_) {
#pragma unroll
                    for (int j = 0; j < 4; ++j) {
                        int row = mh * 64 + mw * 16 + khi * 4 + j;
                        float nxt = rdf(xseq, (long)row * (T_ * INF_) + (long)(t + 1) * INF_ + col, f32o);
                        __builtin_nontemporal_store(bf2u((__bf16)nxt),
                            (unsigned short*)g_infp + row * INFP_ + col);
                    }
                }
                __syncthreads();   // drain NT stores of all waves
                if (tid == 0) {
                    __threadfence();
                    __hip_atomic_fetch_max(&g_dflags[db * SP], t + 1, __ATOMIC_RELAXED, __HIP_MEMORY_SCOPE_AGENT);
                }
            }
            const __bf16* h2 = g_h[(t + 1) & 1] + 2 * B_ * H_;
            const __bf16* pa = h2 + (mh * 64 + mw * 16 + rlo) * H_ + kk * 512 + khi * 8;
            const __bf16* pb = g_Wdec + (long)colc * H_ + kk * 512 + khi * 8;
            f32x4 acc = {};
            bf16x8 a0, a1, b0, b1, c0, c1, d0, d1;
            a0 = ld8(pa); a1 = ld8(pa + 32); b0 = ld8(pb); b1 = ld8(pb + 32);
            c0 = ld8(pa + 64); c1 = ld8(pa + 96); d0 = ld8(pb + 64); d1 = ld8(pb + 96);
            for (int i = 0; i < 8; i += 2) {
                acc = mfma_bf16(a0, b0, acc);
                acc = mfma_bf16(a1, b1, acc);
                if (i + 2 < 8) {
                    int k = (i + 2) << 6;
                    a0 = ld8(pa + k); a1 = ld8(pa + k + 32);
                    b0 = ld8(pb + k); b1 = ld8(pb + k + 32);
                }
                acc = mfma_bf16(c0, d0, acc);
                acc = mfma_bf16(c1, d1, acc);
                if (i + 3 < 8) {
                    int k = (i + 3) << 6;
                    c0 = ld8(pa + k); c1 = ld8(pa + k + 32);
                    d0 = ld8(pb + k); d1 = ld8(pb + k + 32);
                }
            }
            if (kk == 1) {
#pragma unroll
                for (int j = 0; j < 4; ++j)
                    s_acc[(mw * 16 + khi * 4 + j) * 16 + rlo] = acc[j];
            }
            __syncthreads();
            if (kk == 0) {
#pragma unroll
                for (int j = 0; j < 4; ++j)
                    acc[j] += s_acc[(mw * 16 + khi * 4 + j) * 16 + rlo];
                if (col < OUTF_) {
                    const float bias = g_bdec[col];
#pragma unroll
                    for (int j = 0; j < 4; ++j) {
                        int row = mh * 64 + mw * 16 + khi * 4 + j;
                        float ov = acc[j] + bias;
                        long oidx = (long)row * (T_ * OUTF_) + (long)t * OUTF_ + col;
                        if (f32o) __builtin_nontemporal_store(ov, (float*)dout + oidx);
                        else __builtin_nontemporal_store(bf2u((__bf16)ov), (unsigned short*)dout + oidx);
                        if (winf && !gt) {
                            __builtin_nontemporal_store(bf2u((__bf16)ov),
                                (unsigned short*)g_infp + row * INFP_ + col);
                        }
                    }
                }
            }
            __syncthreads();
            if (winf && !gt && tid == 0) {
                __threadfence();
                __hip_atomic_fetch_max(&g_dflags[db * SP], t + 1, __ATOMIC_RELAXED, __HIP_MEMORY_SCOPE_AGENT);
            }
        };

        for (int p = 0; p < T_; ++p) {
            if (p >= 1) decwork(p - 1, true);
            gridbar_w(bid, grp, p + 1);
        }
        decwork(T_ - 1, false);
    } else {
        // ======== MASTER BLOCK (barrier + iready aggregation, RMW polls) ========
        for (int p = 0; p < T_; ++p) {
            const int tgt = p + 1;
            bool ir_done = false;
            for (int it = 0; it < 2000; ++it) {
                if (tid == 0) { s_nf = 0; s_nd = 0; }
                __syncthreads();
                int bad_f = 0, bad_d = 0;
                if (tid < NWORK)
                    bad_f = (__hip_atomic_fetch_max(&g_flags[tid * SP], 0, __ATOMIC_RELAXED, __HIP_MEMORY_SCOPE_AGENT) < tgt);
                if (!ir_done && tid < NDEC)
                    bad_d = (__hip_atomic_fetch_max(&g_dflags[tid * SP], 0, __ATOMIC_RELAXED, __HIP_MEMORY_SCOPE_AGENT) < p);
                if (bad_f) s_nf = 1;
                if (bad_d) s_nd = 1;
                __syncthreads();
                if (!ir_done && !s_nd) {
                    if (tid < 8)
                        __hip_atomic_fetch_max(&g_iready8[tid * SP], p, __ATOMIC_RELAXED, __HIP_MEMORY_SCOPE_AGENT);
                    ir_done = true;
                }
                if (!s_nf) break;
                __builtin_amdgcn_s_sleep(1);
            }
            // all flags arrived => dec work for step p done => publish is safe
            if (!ir_done && tid < 8)
                __hip_atomic_fetch_max(&g_iready8[tid * SP], p, __ATOMIC_RELAXED, __HIP_MEMORY_SCOPE_AGENT);
            __syncthreads();
            if (tid < 8)
                __hip_atomic_fetch_max(&g_gen8[tid * SP], tgt, __ATOMIC_RELAXED, __HIP_MEMORY_SCOPE_AGENT);
        }
    }
}

extern "C" void kernel_launch(void* const* d_in, const int* in_sizes, int n_in,
                              void* d_out, int out_size, void* d_ws, size_t ws_size,
                              hipStream_t stream) {
    const void* xseq = d_in[0];
    detect_k<<<1, 256, 0, stream>>>((const unsigned int*)xseq);
    prep_k<<<2048, 256, 0, stream>>>(d_in[1], d_in[2], d_in[5], d_in[6], d_in[9],
                                     d_in[10], d_in[13], d_in[3], d_in[4], d_in[7],
                                     d_in[8], d_in[11], d_in[12], d_in[14], xseq);
    persist_k<<<NBLK, 512, 0, stream>>>(xseq, d_out);
}

// Round 12
// 6371.486 us; speedup vs baseline: 2.3546x; 2.3546x over previous
//
#include <hip/hip_runtime.h>

#define B_ 128
#define T_ 200
#define INF_ 175
#define INFP_ 192
#define H_ 1024
#define G4_ 4096
#define OUTF_ 175
#define BH3_ (3 * B_ * H_)
#define NCELL 192
#define NDEC 22
#define NWORK (NCELL + NDEC)
#define NBLK (NWORK + 1)
#define SP 16

typedef __bf16 bf16x8 __attribute__((ext_vector_type(8)));
typedef float f32x4 __attribute__((ext_vector_type(4)));

// ---- persistent device state ----
__device__ __attribute__((aligned(16))) __bf16 g_Wih1p[G4_ * INFP_];
__device__ __attribute__((aligned(16))) __bf16 g_Whh1[G4_ * H_];
__device__ __attribute__((aligned(16))) __bf16 g_Wih2[G4_ * H_];
__device__ __attribute__((aligned(16))) __bf16 g_Whh2[G4_ * H_];
__device__ __attribute__((aligned(16))) __bf16 g_Wih3[G4_ * H_];
__device__ __attribute__((aligned(16))) __bf16 g_Whh3[G4_ * H_];
__device__ __attribute__((aligned(16))) __bf16 g_Wdec[OUTF_ * H_];
__device__ float g_bsum[3 * G4_];
__device__ float g_bdec[OUTF_];
__device__ __attribute__((aligned(16))) __bf16 g_h[2][BH3_];
__device__ __attribute__((aligned(16))) __bf16 g_infp[B_ * INFP_];
__device__ int g_isf32;
__device__ int g_flags[256 * SP];
__device__ int g_dflags[32 * SP];
__device__ int g_gen8[8 * SP];
__device__ int g_iready8[8 * SP];

__device__ __forceinline__ f32x4 mfma_bf16(bf16x8 a, bf16x8 b, f32x4 c) {
    return __builtin_amdgcn_mfma_f32_16x16x32_bf16(a, b, c, 0, 0, 0);
}
__device__ __forceinline__ bf16x8 ld8(const __bf16* p) {
    return *reinterpret_cast<const bf16x8*>(p);
}
__device__ __forceinline__ float sigm(float x) { return 1.f / (1.f + expf(-x)); }
__device__ __forceinline__ float rdf(const void* p, long i, int f32) {
    return f32 ? ((const float*)p)[i] : (float)((const __bf16*)p)[i];
}
__device__ __forceinline__ unsigned short bf2u(__bf16 v) {
    union { __bf16 b; unsigned short u; } c; c.b = v; return c.u;
}

// RMW-poll at L3 coherence point + one acquire at exit. Bounded (hang-proof).
__device__ __forceinline__ void spin_rmw(int* addr, int target, int iters) {
    for (int it = 0; it < iters; ++it) {
        if (__hip_atomic_fetch_max(addr, 0, __ATOMIC_RELAXED, __HIP_MEMORY_SCOPE_AGENT) >= target)
            break;
        __builtin_amdgcn_s_sleep(1);
    }
    (void)__hip_atomic_load(addr, __ATOMIC_ACQUIRE, __HIP_MEMORY_SCOPE_AGENT);
}

// ---- dtype probe ----
__global__ void detect_k(const unsigned int* __restrict__ xw) {
    __shared__ int cnt;
    if (threadIdx.x == 0) cnt = 0;
    __syncthreads();
    unsigned int w = xw[threadIdx.x];
    int e = (w >> 7) & 0xFF;
    if (e >= 140) atomicAdd(&cnt, 1);
    __syncthreads();
    if (threadIdx.x == 0) g_isf32 = (cnt >= 16) ? 1 : 0;
}

// ---- prep ----
__global__ void prep_k(const void* Wih1, const void* Whh1, const void* Wih2,
                       const void* Whh2, const void* Wih3, const void* Whh3,
                       const void* Wdec, const void* bih1, const void* bhh1,
                       const void* bih2, const void* bhh2, const void* bih3,
                       const void* bhh3, const void* bdec, const void* xseq) {
    const int f = g_isf32;
    const int idx = blockIdx.x * 256 + threadIdx.x;
    const int stride = gridDim.x * 256;
    if (idx < 256 * SP) g_flags[idx] = 0;
    if (idx < 32 * SP) g_dflags[idx] = 0;
    if (idx < 8 * SP) { g_gen8[idx] = 0; g_iready8[idx] = 0; }
    for (int i = idx; i < G4_ * INFP_; i += stride) {
        int n = i / INFP_, k = i - n * INFP_;
        g_Wih1p[i] = (k < INF_) ? (__bf16)rdf(Wih1, (long)n * INF_ + k, f) : (__bf16)0.f;
    }
    for (int i = idx; i < G4_ * H_; i += stride) {
        g_Whh1[i] = (__bf16)rdf(Whh1, i, f);
        g_Wih2[i] = (__bf16)rdf(Wih2, i, f);
        g_Whh2[i] = (__bf16)rdf(Whh2, i, f);
        g_Wih3[i] = (__bf16)rdf(Wih3, i, f);
        g_Whh3[i] = (__bf16)rdf(Whh3, i, f);
    }
    for (int i = idx; i < OUTF_ * H_; i += stride) g_Wdec[i] = (__bf16)rdf(Wdec, i, f);
    for (int i = idx; i < G4_; i += stride) {
        g_bsum[i]           = rdf(bih1, i, f) + rdf(bhh1, i, f);
        g_bsum[G4_ + i]     = rdf(bih2, i, f) + rdf(bhh2, i, f);
        g_bsum[2 * G4_ + i] = rdf(bih3, i, f) + rdf(bhh3, i, f);
    }
    for (int i = idx; i < OUTF_; i += stride) g_bdec[i] = rdf(bdec, i, f);
    for (int i = idx; i < 2 * BH3_; i += stride) (&g_h[0][0])[i] = (__bf16)0.f;
    for (int i = idx; i < B_ * INFP_; i += stride) {
        int b = i / INFP_, k = i - b * INFP_;
        g_infp[i] = (k < INF_) ? (__bf16)rdf(xseq, (long)b * (T_ * INF_) + k, f) : (__bf16)0.f;
    }
}

// ---- worker barrier (r11, proven) ----
__device__ __forceinline__ void gridbar_w(int bid, int grp, int target) {
    __syncthreads();
    if (threadIdx.x == 0) {
        __threadfence();
        __hip_atomic_fetch_max(&g_flags[bid * SP], target, __ATOMIC_RELAXED, __HIP_MEMORY_SCOPE_AGENT);
        spin_rmw(&g_gen8[grp * SP], target, 4000);
    }
    __syncthreads();
}

// ---- persistent kernel ----
__global__ __launch_bounds__(512, 1) void persist_k(const void* __restrict__ xseq,
                                                    void* __restrict__ dout) {
    __shared__ char s_tile[2][2][16384];   // [buf][op][128 rows x 64 cols bf16] 64KB
    __shared__ float s_acc[B_ * 4 * 16];   // 32KB
    __shared__ float s_c[B_ * 16];         // 8KB
    __shared__ int s_nf, s_nd;
    const int bid = blockIdx.x;
    const int grp = bid & 7;
    const int tid = threadIdx.x;
    const int lane = tid & 63;
    const int wid = tid >> 6;
    const int rlo = lane & 15, khi = lane >> 4;
    const int f32o = g_isf32;
    // swizzled LDS read byte-offsets within a 128B tile row (T2 pattern)
    const int r7l = rlo & 7;
    const int sw0 = (khi ^ r7l) * 16;
    const int sw1 = ((khi + 4) ^ r7l) * 16;

    if (bid < NCELL) {
        // ================= CELL BLOCK =================
        const int L = bid >> 6;
        const int hc0 = (bid & 63) << 4;
        const int op = wid >> 2;         // 0: x-GEMM, 1: recurrent GEMM
        const int g = wid & 3;           // gate
        const float* bs = g_bsum + L * G4_;

        const __bf16* Bm; int K;
        if (op == 0) {
            if (L == 0) { Bm = g_Wih1p; K = INFP_; }
            else        { Bm = (L == 1) ? g_Wih2 : g_Wih3; K = H_; }
        } else {
            Bm = (L == 0) ? g_Whh1 : (L == 1) ? g_Whh2 : g_Whh3; K = H_;
        }
        const __bf16* wp = Bm + (long)(g * H_ + hc0 + rlo) * K + khi * 8;
        bf16x8 wreg[32];
        if (K == INFP_) {
#pragma unroll
            for (int c = 0; c < 6; ++c) wreg[c] = ld8(wp + c * 32);
        } else {
#pragma unroll
            for (int c = 0; c < 32; ++c) wreg[c] = ld8(wp + c * 32);
        }

        // staging lambdas: thread covers row=tid>>2 (0..127), quarter q=tid&3
        const int strow = tid >> 2, stq = tid & 3, str7 = strow & 7;
        auto ldchunk = [&](const __bf16* src, int sA, int k0, bf16x8& v0, bf16x8& v1) {
            const __bf16* pr = src + (long)strow * sA + k0 + stq * 8;
            v0 = ld8(pr);
            v1 = ld8(pr + 32);
        };
        auto wrchunk = [&](char* tile, bf16x8 v0, bf16x8 v1) {
            char* pb = tile + strow * 128;
            *(bf16x8*)(pb + ((stq ^ str7) * 16)) = v0;
            *(bf16x8*)(pb + (((stq + 4) ^ str7) * 16)) = v1;
        };

        for (int i = tid; i < B_ * 16; i += 512) s_c[i] = 0.f;
        __syncthreads();

        for (int p = 0; p < T_; ++p) {
            const __bf16* hin = g_h[p & 1];
            const __bf16* Apx; int sAx, nx;
            if (L == 0) { Apx = g_infp; sAx = INFP_; nx = 3; }
            else        { Apx = hin + (L - 1) * B_ * H_; sAx = H_; nx = 16; }
            const __bf16* Aph = hin + L * B_ * H_;

            // L0 waits for this step's in_frame (block-wide, before x staging)
            if (L == 0 && p > 0) {
                if (tid == 0) spin_rmw(&g_iready8[grp * SP], p, 3000);
                __syncthreads();
            }

            // prologue: stage chunk 0, issue loads for chunk 1
            bf16x8 rx0, rx1, rh0, rh1;
            ldchunk(Aph, H_, 0, rh0, rh1);
            ldchunk(Apx, sAx, 0, rx0, rx1);
            wrchunk(&s_tile[0][1][0], rh0, rh1);
            wrchunk(&s_tile[0][0][0], rx0, rx1);
            ldchunk(Aph, H_, 64, rh0, rh1);
            ldchunk(Apx, sAx, 64, rx0, rx1);
            __syncthreads();

            f32x4 acc[8] = {};
            int buf = 0;
#pragma unroll
            for (int i = 0; i < 16; ++i) {
                // write chunk i+1 (regs loaded last iter), issue loads chunk i+2
                if (i < 15) wrchunk(&s_tile[buf ^ 1][1][0], rh0, rh1);
                if (i + 1 < nx) wrchunk(&s_tile[buf ^ 1][0][0], rx0, rx1);
                if (i < 14) ldchunk(Aph, H_, (i + 2) * 64, rh0, rh1);
                if (i + 2 < nx) ldchunk(Apx, sAx, (i + 2) * 64, rx0, rx1);
                // compute chunk i of my operand from LDS
                if (op == 1 || i < nx) {
                    const char* tb = &s_tile[buf][op][0];
#pragma unroll
                    for (int mf = 0; mf < 8; ++mf) {
                        const char* rb = tb + (mf * 16 + rlo) * 128;
                        acc[mf] = mfma_bf16(*(const bf16x8*)(rb + sw0), wreg[2 * i], acc[mf]);
                        acc[mf] = mfma_bf16(*(const bf16x8*)(rb + sw1), wreg[2 * i + 1], acc[mf]);
                    }
                }
                __syncthreads();
                buf ^= 1;
            }

            // operand-split reduce through LDS
            if (op == 1) {
#pragma unroll
                for (int mf = 0; mf < 8; ++mf)
#pragma unroll
                    for (int j = 0; j < 4; ++j) {
                        int r = mf * 16 + khi * 4 + j;
                        s_acc[(r * 4 + g) * 16 + rlo] = acc[mf][j];
                    }
            }
            __syncthreads();
            if (op == 0) {
#pragma unroll
                for (int mf = 0; mf < 8; ++mf)
#pragma unroll
                    for (int j = 0; j < 4; ++j) {
                        int r = mf * 16 + khi * 4 + j;
                        s_acc[(r * 4 + g) * 16 + rlo] += acc[mf][j];
                    }
            }
            __syncthreads();

            // epilogue: 8 waves x 16 rows, 4 cols/lane; h out = NT store
            {
                const int r = wid * 16 + rlo;
                const int hq = khi;
                f32x4 ga = *(const f32x4*)&s_acc[(r * 4 + 0) * 16 + hq * 4];
                f32x4 gf = *(const f32x4*)&s_acc[(r * 4 + 1) * 16 + hq * 4];
                f32x4 gg = *(const f32x4*)&s_acc[(r * 4 + 2) * 16 + hq * 4];
                f32x4 go = *(const f32x4*)&s_acc[(r * 4 + 3) * 16 + hq * 4];
                f32x4 cv = *(const f32x4*)&s_c[r * 16 + hq * 4];
                unsigned long long hbits;
                unsigned short* hp = (unsigned short*)&hbits;
#pragma unroll
                for (int e = 0; e < 4; ++e) {
                    int col = hc0 + hq * 4 + e;
                    float gi_ = ga[e] + bs[0 * H_ + col];
                    float gf_ = gf[e] + bs[1 * H_ + col];
                    float gg_ = gg[e] + bs[2 * H_ + col];
                    float go_ = go[e] + bs[3 * H_ + col];
                    float cn = sigm(gf_) * cv[e] + sigm(gi_) * tanhf(gg_);
                    cv[e] = cn;
                    hp[e] = bf2u((__bf16)(sigm(go_) * tanhf(cn)));
                }
                *(f32x4*)&s_c[r * 16 + hq * 4] = cv;
                __bf16* hdst = g_h[(p + 1) & 1] + L * B_ * H_ + r * H_ + hc0 + hq * 4;
                __builtin_nontemporal_store(hbits, (unsigned long long*)hdst);
            }
            gridbar_w(bid, grp, p + 1);
        }
    } else if (bid < NWORK) {
        // ================= DEC BLOCK =================
        const int db = bid - NCELL;
        const int ntile = db % 11, mh = db / 11;
        const int kk = wid >> 2;         // K half
        const int mw = wid & 3;          // m-frag
        const int col = ntile * 16 + rlo;
        const int colc = (col < OUTF_) ? col : (OUTF_ - 1);

        // preload this wave's Wdec half into registers (held 200 steps)
        const __bf16* pb = g_Wdec + (long)colc * H_ + khi * 8;
        bf16x8 dw[16];
#pragma unroll
        for (int c = 0; c < 16; ++c) dw[c] = ld8(pb + (kk * 16 + c) * 32);

        const int strow = tid >> 3, stc8 = tid & 7, str7 = strow & 7;
        char* const dt0 = &s_tile[0][0][0];
        char* const dt1 = &s_tile[1][0][0];

        auto decwork = [&](int t, bool winf) {
            const bool gt = (((t + 1) % 10) < 5);
            if (winf && gt) {   // gt fast-path: infp(t+1) from xseq before GEMM
                if (kk == 0 && col < OUTF_) {
#pragma unroll
                    for (int j = 0; j < 4; ++j) {
                        int row = mh * 64 + mw * 16 + khi * 4 + j;
                        float nxt = rdf(xseq, (long)row * (T_ * INF_) + (long)(t + 1) * INF_ + col, f32o);
                        __builtin_nontemporal_store(bf2u((__bf16)nxt),
                            (unsigned short*)g_infp + row * INFP_ + col);
                    }
                }
                __syncthreads();
                if (tid == 0) {
                    __threadfence();
                    __hip_atomic_fetch_max(&g_dflags[db * SP], t + 1, __ATOMIC_RELAXED, __HIP_MEMORY_SCOPE_AGENT);
                }
            }
            const __bf16* h2 = g_h[(t + 1) & 1] + 2 * B_ * H_;
            const __bf16* hrow = h2 + (long)(mh * 64 + strow) * H_ + stc8 * 8;
            // prologue
            bf16x8 rv = ld8(hrow);
            *(bf16x8*)(dt0 + strow * 128 + ((stc8 ^ str7) * 16)) = rv;
            rv = ld8(hrow + 64);
            __syncthreads();
            f32x4 acc = {};
            int b = 0;
#pragma unroll
            for (int i = 0; i < 16; ++i) {
                if (i < 15) *(bf16x8*)((b ? dt0 : dt1) + strow * 128 + ((stc8 ^ str7) * 16)) = rv;
                if (i < 14) rv = ld8(hrow + (i + 2) * 64);
                {
                    const char* rb = (b ? dt1 : dt0) + (mw * 16 + rlo) * 128;
                    bf16x8 a0 = *(const bf16x8*)(rb + sw0);
                    bf16x8 a1 = *(const bf16x8*)(rb + sw1);
                    if (i < 8) {
                        if (kk == 0) {
                            acc = mfma_bf16(a0, dw[2 * i], acc);
                            acc = mfma_bf16(a1, dw[2 * i + 1], acc);
                        }
                    } else {
                        if (kk == 1) {
                            acc = mfma_bf16(a0, dw[2 * i - 16], acc);
                            acc = mfma_bf16(a1, dw[2 * i - 15], acc);
                        }
                    }
                }
                __syncthreads();
                b ^= 1;
            }
            // K-split reduce + output
            if (kk == 1) {
#pragma unroll
                for (int j = 0; j < 4; ++j)
                    s_acc[(mw * 16 + khi * 4 + j) * 16 + rlo] = acc[j];
            }
            __syncthreads();
            if (kk == 0) {
#pragma unroll
                for (int j = 0; j < 4; ++j)
                    acc[j] += s_acc[(mw * 16 + khi * 4 + j) * 16 + rlo];
                if (col < OUTF_) {
                    const float bias = g_bdec[col];
#pragma unroll
                    for (int j = 0; j < 4; ++j) {
                        int row = mh * 64 + mw * 16 + khi * 4 + j;
                        float ov = acc[j] + bias;
                        long oidx = (long)row * (T_ * OUTF_) + (long)t * OUTF_ + col;
                        if (f32o) __builtin_nontemporal_store(ov, (float*)dout + oidx);
                        else __builtin_nontemporal_store(bf2u((__bf16)ov), (unsigned short*)dout + oidx);
                        if (winf && !gt) {
                            __builtin_nontemporal_store(bf2u((__bf16)ov),
                                (unsigned short*)g_infp + row * INFP_ + col);
                        }
                    }
                }
            }
            __syncthreads();
            if (winf && !gt && tid == 0) {
                __threadfence();
                __hip_atomic_fetch_max(&g_dflags[db * SP], t + 1, __ATOMIC_RELAXED, __HIP_MEMORY_SCOPE_AGENT);
            }
        };

        for (int p = 0; p < T_; ++p) {
            if (p >= 1) decwork(p - 1, true);
            gridbar_w(bid, grp, p + 1);
        }
        decwork(T_ - 1, false);
    } else {
        // ======== MASTER BLOCK (r11, proven) ========
        for (int p = 0; p < T_; ++p) {
            const int tgt = p + 1;
            bool ir_done = false;
            for (int it = 0; it < 2000; ++it) {
                if (tid == 0) { s_nf = 0; s_nd = 0; }
                __syncthreads();
                int bad_f = 0, bad_d = 0;
                if (tid < NWORK)
                    bad_f = (__hip_atomic_fetch_max(&g_flags[tid * SP], 0, __ATOMIC_RELAXED, __HIP_MEMORY_SCOPE_AGENT) < tgt);
                if (!ir_done && tid < NDEC)
                    bad_d = (__hip_atomic_fetch_max(&g_dflags[tid * SP], 0, __ATOMIC_RELAXED, __HIP_MEMORY_SCOPE_AGENT) < p);
                if (bad_f) s_nf = 1;
                if (bad_d) s_nd = 1;
                __syncthreads();
                if (!ir_done && !s_nd) {
                    if (tid < 8)
                        __hip_atomic_fetch_max(&g_iready8[tid * SP], p, __ATOMIC_RELAXED, __HIP_MEMORY_SCOPE_AGENT);
                    ir_done = true;
                }
                if (!s_nf) break;
                __builtin_amdgcn_s_sleep(1);
            }
            if (!ir_done && tid < 8)
                __hip_atomic_fetch_max(&g_iready8[tid * SP], p, __ATOMIC_RELAXED, __HIP_MEMORY_SCOPE_AGENT);
            __syncthreads();
            if (tid < 8)
                __hip_atomic_fetch_max(&g_gen8[tid * SP], tgt, __ATOMIC_RELAXED, __HIP_MEMORY_SCOPE_AGENT);
        }
    }
}

extern "C" void kernel_launch(void* const* d_in, const int* in_sizes, int n_in,
                              void* d_out, int out_size, void* d_ws, size_t ws_size,
                              hipStream_t stream) {
    const void* xseq = d_in[0];
    detect_k<<<1, 256, 0, stream>>>((const unsigned int*)xseq);
    prep_k<<<2048, 256, 0, stream>>>(d_in[1], d_in[2], d_in[5], d_in[6], d_in[9],
                                     d_in[10], d_in[13], d_in[3], d_in[4], d_in[7],
                                     d_in[8], d_in[11], d_in[12], d_in[14], xseq);
    persist_k<<<NBLK, 512, 0, stream>>>(xseq, d_out);
}

// Round 13
// 6064.548 us; speedup vs baseline: 2.4737x; 1.0506x over previous
//
#include <hip/hip_runtime.h>

#define B_ 128
#define T_ 200
#define INF_ 175
#define INFP_ 192
#define H_ 1024
#define G4_ 4096
#define OUTF_ 175
#define BH3_ (3 * B_ * H_)
#define NCELL 192
#define NDEC 22
#define NWORK (NCELL + NDEC)
#define NBLK (NWORK + 1)
#define SP 16

typedef __bf16 bf16x8 __attribute__((ext_vector_type(8)));
typedef float f32x4 __attribute__((ext_vector_type(4)));

// ---- persistent device state ----
__device__ __attribute__((aligned(16))) __bf16 g_Wih1p[G4_ * INFP_];
__device__ __attribute__((aligned(16))) __bf16 g_Whh1[G4_ * H_];
__device__ __attribute__((aligned(16))) __bf16 g_Wih2[G4_ * H_];
__device__ __attribute__((aligned(16))) __bf16 g_Whh2[G4_ * H_];
__device__ __attribute__((aligned(16))) __bf16 g_Wih3[G4_ * H_];
__device__ __attribute__((aligned(16))) __bf16 g_Whh3[G4_ * H_];
__device__ __attribute__((aligned(16))) __bf16 g_Wdec[OUTF_ * H_];
__device__ float g_bsum[3 * G4_];
__device__ float g_bdec[OUTF_];
__device__ __attribute__((aligned(16))) __bf16 g_h[2][BH3_];
__device__ __attribute__((aligned(16))) __bf16 g_infp[B_ * INFP_];
__device__ __attribute__((aligned(16))) __bf16 g_xp[(long)T_ * B_ * INFP_]; // padded bf16 xseq
__device__ int g_isf32;
__device__ int g_flags[256 * SP];
__device__ int g_dflags[32 * SP];
__device__ int g_gen8[8 * SP];
__device__ int g_iready8[8 * SP];

__device__ __forceinline__ f32x4 mfma_bf16(bf16x8 a, bf16x8 b, f32x4 c) {
    return __builtin_amdgcn_mfma_f32_16x16x32_bf16(a, b, c, 0, 0, 0);
}
__device__ __forceinline__ bf16x8 ld8(const __bf16* p) {
    return *reinterpret_cast<const bf16x8*>(p);
}
__device__ __forceinline__ float sigm(float x) { return 1.f / (1.f + expf(-x)); }
__device__ __forceinline__ float rdf(const void* p, long i, int f32) {
    return f32 ? ((const float*)p)[i] : (float)((const __bf16*)p)[i];
}
__device__ __forceinline__ unsigned short bf2u(__bf16 v) {
    union { __bf16 b; unsigned short u; } c; c.b = v; return c.u;
}

// RMW-poll at L3 coherence point + one acquire at exit. Bounded (hang-proof).
__device__ __forceinline__ void spin_rmw(int* addr, int target, int iters) {
    for (int it = 0; it < iters; ++it) {
        if (__hip_atomic_fetch_max(addr, 0, __ATOMIC_RELAXED, __HIP_MEMORY_SCOPE_AGENT) >= target)
            break;
        __builtin_amdgcn_s_sleep(1);
    }
    (void)__hip_atomic_load(addr, __ATOMIC_ACQUIRE, __HIP_MEMORY_SCOPE_AGENT);
}

// ---- dtype probe ----
__global__ void detect_k(const unsigned int* __restrict__ xw) {
    __shared__ int cnt;
    if (threadIdx.x == 0) cnt = 0;
    __syncthreads();
    unsigned int w = xw[threadIdx.x];
    int e = (w >> 7) & 0xFF;
    if (e >= 140) atomicAdd(&cnt, 1);
    __syncthreads();
    if (threadIdx.x == 0) g_isf32 = (cnt >= 16) ? 1 : 0;
}

// ---- prep ----
__global__ void prep_k(const void* Wih1, const void* Whh1, const void* Wih2,
                       const void* Whh2, const void* Wih3, const void* Whh3,
                       const void* Wdec, const void* bih1, const void* bhh1,
                       const void* bih2, const void* bhh2, const void* bih3,
                       const void* bhh3, const void* bdec, const void* xseq) {
    const int f = g_isf32;
    const int idx = blockIdx.x * 256 + threadIdx.x;
    const int stride = gridDim.x * 256;
    if (idx < 256 * SP) g_flags[idx] = 0;
    if (idx < 32 * SP) g_dflags[idx] = 0;
    if (idx < 8 * SP) { g_gen8[idx] = 0; g_iready8[idx] = 0; }
    for (int i = idx; i < G4_ * INFP_; i += stride) {
        int n = i / INFP_, k = i - n * INFP_;
        g_Wih1p[i] = (k < INF_) ? (__bf16)rdf(Wih1, (long)n * INF_ + k, f) : (__bf16)0.f;
    }
    for (int i = idx; i < G4_ * H_; i += stride) {
        g_Whh1[i] = (__bf16)rdf(Whh1, i, f);
        g_Wih2[i] = (__bf16)rdf(Wih2, i, f);
        g_Whh2[i] = (__bf16)rdf(Whh2, i, f);
        g_Wih3[i] = (__bf16)rdf(Wih3, i, f);
        g_Whh3[i] = (__bf16)rdf(Whh3, i, f);
    }
    for (int i = idx; i < OUTF_ * H_; i += stride) g_Wdec[i] = (__bf16)rdf(Wdec, i, f);
    for (int i = idx; i < G4_; i += stride) {
        g_bsum[i]           = rdf(bih1, i, f) + rdf(bhh1, i, f);
        g_bsum[G4_ + i]     = rdf(bih2, i, f) + rdf(bhh2, i, f);
        g_bsum[2 * G4_ + i] = rdf(bih3, i, f) + rdf(bhh3, i, f);
    }
    for (int i = idx; i < OUTF_; i += stride) g_bdec[i] = rdf(bdec, i, f);
    for (int i = idx; i < 2 * BH3_; i += stride) (&g_h[0][0])[i] = (__bf16)0.f;
    for (int i = idx; i < B_ * INFP_; i += stride) g_infp[i] = (__bf16)0.f;
    // padded bf16 xseq: g_xp[t][b][k] = k<INF ? xseq[b][t][k] : 0
    const long total = (long)T_ * B_ * INFP_;
    for (long i = idx; i < total; i += stride) {
        int k = (int)(i % INFP_);
        long bt = i / INFP_;
        int b = (int)(bt % B_);
        int t = (int)(bt / B_);
        g_xp[((long)t * B_ + b) * INFP_ + k] =
            (k < INF_) ? (__bf16)rdf(xseq, (long)b * (T_ * INF_) + (long)t * INF_ + k, f)
                       : (__bf16)0.f;
    }
}

// ---- worker barrier (r11, proven) ----
__device__ __forceinline__ void gridbar_w(int bid, int grp, int target) {
    __syncthreads();
    if (threadIdx.x == 0) {
        __threadfence();
        __hip_atomic_fetch_max(&g_flags[bid * SP], target, __ATOMIC_RELAXED, __HIP_MEMORY_SCOPE_AGENT);
        spin_rmw(&g_gen8[grp * SP], target, 4000);
    }
    __syncthreads();
}

// ---- persistent kernel ----
__global__ __launch_bounds__(512, 1) void persist_k(const void* __restrict__ xseq,
                                                    void* __restrict__ dout) {
    __shared__ char s_tile[2][2][16384];   // [buf][op][128 rows x 64 cols bf16] 64KB
    __shared__ float s_acc[B_ * 4 * 16];   // 32KB
    __shared__ float s_c[B_ * 16];         // 8KB
    __shared__ int s_nf, s_nd;
    const int bid = blockIdx.x;
    const int grp = bid & 7;
    const int tid = threadIdx.x;
    const int lane = tid & 63;
    const int wid = tid >> 6;
    const int rlo = lane & 15, khi = lane >> 4;
    const int f32o = g_isf32;
    const int r7l = rlo & 7;
    const int sw0 = (khi ^ r7l) * 16;
    const int sw1 = ((khi + 4) ^ r7l) * 16;

    if (bid < NCELL) {
        // ================= CELL BLOCK =================
        const int L = bid >> 6;
        const int hc0 = (bid & 63) << 4;
        const int op = wid >> 2;         // 0: x-GEMM, 1: recurrent GEMM
        const int g = wid & 3;           // gate
        const float* bs = g_bsum + L * G4_;
        const int XOFF = (L == 0) ? 13 : 0;   // L0 x-chunks run at loop idx 13..15

        const __bf16* Bm; int K;
        if (op == 0) {
            if (L == 0) { Bm = g_Wih1p; K = INFP_; }
            else        { Bm = (L == 1) ? g_Wih2 : g_Wih3; K = H_; }
        } else {
            Bm = (L == 0) ? g_Whh1 : (L == 1) ? g_Whh2 : g_Whh3; K = H_;
        }
        const __bf16* wp = Bm + (long)(g * H_ + hc0 + rlo) * K + khi * 8;
        bf16x8 wreg[32];
        if (K == INFP_) {
#pragma unroll
            for (int c = 0; c < 6; ++c) wreg[c] = ld8(wp + c * 32);
        } else {
#pragma unroll
            for (int c = 0; c < 32; ++c) wreg[c] = ld8(wp + c * 32);
        }

        const int strow = tid >> 2, stq = tid & 3, str7 = strow & 7;
        auto ldchunk = [&](const __bf16* src, int sA, int k0, bf16x8& v0, bf16x8& v1) {
            const __bf16* pr = src + (long)strow * sA + k0 + stq * 8;
            v0 = ld8(pr);
            v1 = ld8(pr + 32);
        };
        auto wrchunk = [&](char* tile, bf16x8 v0, bf16x8 v1) {
            char* pb = tile + strow * 128;
            *(bf16x8*)(pb + ((stq ^ str7) * 16)) = v0;
            *(bf16x8*)(pb + (((stq + 4) ^ str7) * 16)) = v1;
        };

        for (int i = tid; i < B_ * 16; i += 512) s_c[i] = 0.f;
        __syncthreads();

        for (int p = 0; p < T_; ++p) {
            const bool gt = ((p % 10) < 5);
            const __bf16* hin = g_h[p & 1];
            const __bf16* Apx; int sAx, nx;
            if (L == 0) {
                Apx = gt ? (g_xp + (long)p * B_ * INFP_) : g_infp;
                sAx = INFP_; nx = 3;
            } else {
                Apx = hin + (L - 1) * B_ * H_; sAx = H_; nx = 16;
            }
            const __bf16* Aph = hin + L * B_ * H_;
            const bool needwait = (L == 0) && !gt;   // dec(p-1) must have written infp

            // prologue: stage h chunk 0 (+ x chunk 0 when XOFF==0)
            bf16x8 rx0, rx1, rh0, rh1;
            ldchunk(Aph, H_, 0, rh0, rh1);
            if (XOFF == 0) ldchunk(Apx, sAx, 0, rx0, rx1);
            wrchunk(&s_tile[0][1][0], rh0, rh1);
            if (XOFF == 0) wrchunk(&s_tile[0][0][0], rx0, rx1);
            ldchunk(Aph, H_, 64, rh0, rh1);
            if (XOFF == 0) ldchunk(Apx, sAx, 64, rx0, rx1);
            __syncthreads();

            f32x4 acc[8] = {};
            int buf = 0;
#pragma unroll
            for (int i = 0; i < 16; ++i) {
                // write chunk i+1 (regs loaded last iter)
                if (i < 15) wrchunk(&s_tile[buf ^ 1][1][0], rh0, rh1);
                {
                    int xj = i + 1 - XOFF;
                    if (xj >= 0 && xj < nx) wrchunk(&s_tile[buf ^ 1][0][0], rx0, rx1);
                }
                // L0 non-gt: wait for infp just before issuing its first x load
                if (i == 11 && needwait) {
                    if (tid == 0) spin_rmw(&g_iready8[grp * SP], p, 3000);
                    __syncthreads();
                }
                // issue loads for chunk i+2
                if (i < 14) ldchunk(Aph, H_, (i + 2) * 64, rh0, rh1);
                {
                    int xj = i + 2 - XOFF;
                    if (xj >= 0 && xj < nx) ldchunk(Apx, sAx, xj * 64, rx0, rx1);
                }
                // compute chunk i of my operand from LDS
                if (op == 1) {
                    const char* tb = &s_tile[buf][1][0];
#pragma unroll
                    for (int mf = 0; mf < 8; ++mf) {
                        const char* rb = tb + (mf * 16 + rlo) * 128;
                        acc[mf] = mfma_bf16(*(const bf16x8*)(rb + sw0), wreg[2 * i], acc[mf]);
                        acc[mf] = mfma_bf16(*(const bf16x8*)(rb + sw1), wreg[2 * i + 1], acc[mf]);
                    }
                } else {
                    int xj = i - XOFF;
                    if (xj >= 0 && xj < nx) {
                        const char* tb = &s_tile[buf][0][0];
#pragma unroll
                        for (int mf = 0; mf < 8; ++mf) {
                            const char* rb = tb + (mf * 16 + rlo) * 128;
                            acc[mf] = mfma_bf16(*(const bf16x8*)(rb + sw0), wreg[2 * xj], acc[mf]);
                            acc[mf] = mfma_bf16(*(const bf16x8*)(rb + sw1), wreg[2 * xj + 1], acc[mf]);
                        }
                    }
                }
                __syncthreads();
                buf ^= 1;
            }

            // operand-split reduce through LDS
            if (op == 1) {
#pragma unroll
                for (int mf = 0; mf < 8; ++mf)
#pragma unroll
                    for (int j = 0; j < 4; ++j) {
                        int r = mf * 16 + khi * 4 + j;
                        s_acc[(r * 4 + g) * 16 + rlo] = acc[mf][j];
                    }
            }
            __syncthreads();
            if (op == 0) {
#pragma unroll
                for (int mf = 0; mf < 8; ++mf)
#pragma unroll
                    for (int j = 0; j < 4; ++j) {
                        int r = mf * 16 + khi * 4 + j;
                        s_acc[(r * 4 + g) * 16 + rlo] += acc[mf][j];
                    }
            }
            __syncthreads();

            // epilogue: 8 waves x 16 rows, 4 cols/lane; h out = NT store
            {
                const int r = wid * 16 + rlo;
                const int hq = khi;
                f32x4 ga = *(const f32x4*)&s_acc[(r * 4 + 0) * 16 + hq * 4];
                f32x4 gf = *(const f32x4*)&s_acc[(r * 4 + 1) * 16 + hq * 4];
                f32x4 gg = *(const f32x4*)&s_acc[(r * 4 + 2) * 16 + hq * 4];
                f32x4 go = *(const f32x4*)&s_acc[(r * 4 + 3) * 16 + hq * 4];
                f32x4 cv = *(const f32x4*)&s_c[r * 16 + hq * 4];
                unsigned long long hbits;
                unsigned short* hp = (unsigned short*)&hbits;
#pragma unroll
                for (int e = 0; e < 4; ++e) {
                    int col = hc0 + hq * 4 + e;
                    float gi_ = ga[e] + bs[0 * H_ + col];
                    float gf_ = gf[e] + bs[1 * H_ + col];
                    float gg_ = gg[e] + bs[2 * H_ + col];
                    float go_ = go[e] + bs[3 * H_ + col];
                    float cn = sigm(gf_) * cv[e] + sigm(gi_) * tanhf(gg_);
                    cv[e] = cn;
                    hp[e] = bf2u((__bf16)(sigm(go_) * tanhf(cn)));
                }
                *(f32x4*)&s_c[r * 16 + hq * 4] = cv;
                __bf16* hdst = g_h[(p + 1) & 1] + L * B_ * H_ + r * H_ + hc0 + hq * 4;
                __builtin_nontemporal_store(hbits, (unsigned long long*)hdst);
            }
            gridbar_w(bid, grp, p + 1);
        }
    } else if (bid < NWORK) {
        // ================= DEC BLOCK =================
        const int db = bid - NCELL;
        const int ntile = db % 11, mh = db / 11;
        const int kk = wid >> 2;
        const int mw = wid & 3;
        const int col = ntile * 16 + rlo;
        const int colc = (col < OUTF_) ? col : (OUTF_ - 1);

        const __bf16* pb = g_Wdec + (long)colc * H_ + khi * 8;
        bf16x8 dw[16];
#pragma unroll
        for (int c = 0; c < 16; ++c) dw[c] = ld8(pb + (kk * 16 + c) * 32);

        const int strow = tid >> 3, stc8 = tid & 7, str7 = strow & 7;
        char* const dt0 = &s_tile[0][0][0];
        char* const dt1 = &s_tile[1][0][0];

        auto decwork = [&](int t, bool winf) {
            const bool gtn = (((t + 1) % 10) < 5);   // next step uses ground truth?
            const __bf16* h2 = g_h[(t + 1) & 1] + 2 * B_ * H_;
            const __bf16* hrow = h2 + (long)(mh * 64 + strow) * H_ + stc8 * 8;
            bf16x8 rv = ld8(hrow);
            *(bf16x8*)(dt0 + strow * 128 + ((stc8 ^ str7) * 16)) = rv;
            rv = ld8(hrow + 64);
            __syncthreads();
            f32x4 acc = {};
            int b = 0;
#pragma unroll
            for (int i = 0; i < 16; ++i) {
                if (i < 15) *(bf16x8*)((b ? dt0 : dt1) + strow * 128 + ((stc8 ^ str7) * 16)) = rv;
                if (i < 14) rv = ld8(hrow + (i + 2) * 64);
                {
                    const char* rb = (b ? dt1 : dt0) + (mw * 16 + rlo) * 128;
                    bf16x8 a0 = *(const bf16x8*)(rb + sw0);
                    bf16x8 a1 = *(const bf16x8*)(rb + sw1);
                    if (i < 8) {
                        if (kk == 0) {
                            acc = mfma_bf16(a0, dw[2 * i], acc);
                            acc = mfma_bf16(a1, dw[2 * i + 1], acc);
                        }
                    } else {
                        if (kk == 1) {
                            acc = mfma_bf16(a0, dw[2 * i - 16], acc);
                            acc = mfma_bf16(a1, dw[2 * i - 15], acc);
                        }
                    }
                }
                __syncthreads();
                b ^= 1;
            }
            if (kk == 1) {
#pragma unroll
                for (int j = 0; j < 4; ++j)
                    s_acc[(mw * 16 + khi * 4 + j) * 16 + rlo] = acc[j];
            }
            __syncthreads();
            if (kk == 0) {
#pragma unroll
                for (int j = 0; j < 4; ++j)
                    acc[j] += s_acc[(mw * 16 + khi * 4 + j) * 16 + rlo];
                if (col < OUTF_) {
                    const float bias = g_bdec[col];
#pragma unroll
                    for (int j = 0; j < 4; ++j) {
                        int row = mh * 64 + mw * 16 + khi * 4 + j;
                        float ov = acc[j] + bias;
                        long oidx = (long)row * (T_ * OUTF_) + (long)t * OUTF_ + col;
                        if (f32o) __builtin_nontemporal_store(ov, (float*)dout + oidx);
                        else __builtin_nontemporal_store(bf2u((__bf16)ov), (unsigned short*)dout + oidx);
                        if (winf && !gtn) {   // infp needed only when step t+1 is non-gt
                            __builtin_nontemporal_store(bf2u((__bf16)ov),
                                (unsigned short*)g_infp + row * INFP_ + col);
                        }
                    }
                }
            }
            __syncthreads();
            if (tid == 0) {
                __threadfence();
                __hip_atomic_fetch_max(&g_dflags[db * SP], t + 1, __ATOMIC_RELAXED, __HIP_MEMORY_SCOPE_AGENT);
            }
        };

        for (int p = 0; p < T_; ++p) {
            if (p >= 1) decwork(p - 1, true);
            gridbar_w(bid, grp, p + 1);
        }
        decwork(T_ - 1, false);
    } else {
        // ======== MASTER BLOCK (r11, proven) ========
        for (int p = 0; p < T_; ++p) {
            const int tgt = p + 1;
            bool ir_done = false;
            for (int it = 0; it < 2000; ++it) {
                if (tid == 0) { s_nf = 0; s_nd = 0; }
                __syncthreads();
                int bad_f = 0, bad_d = 0;
                if (tid < NWORK)
                    bad_f = (__hip_atomic_fetch_max(&g_flags[tid * SP], 0, __ATOMIC_RELAXED, __HIP_MEMORY_SCOPE_AGENT) < tgt);
                if (!ir_done && tid < NDEC)
                    bad_d = (__hip_atomic_fetch_max(&g_dflags[tid * SP], 0, __ATOMIC_RELAXED, __HIP_MEMORY_SCOPE_AGENT) < p);
                if (bad_f) s_nf = 1;
                if (bad_d) s_nd = 1;
                __syncthreads();
                if (!ir_done && !s_nd) {
                    if (tid < 8)
                        __hip_atomic_fetch_max(&g_iready8[tid * SP], p, __ATOMIC_RELAXED, __HIP_MEMORY_SCOPE_AGENT);
                    ir_done = true;
                }
                if (!s_nf) break;
                __builtin_amdgcn_s_sleep(1);
            }
            if (!ir_done && tid < 8)
                __hip_atomic_fetch_max(&g_iready8[tid * SP], p, __ATOMIC_RELAXED, __HIP_MEMORY_SCOPE_AGENT);
            __syncthreads();
            if (tid < 8)
                __hip_atomic_fetch_max(&g_gen8[tid * SP], tgt, __ATOMIC_RELAXED, __HIP_MEMORY_SCOPE_AGENT);
        }
    }
}

extern "C" void kernel_launch(void* const* d_in, const int* in_sizes, int n_in,
                              void* d_out, int out_size, void* d_ws, size_t ws_size,
                              hipStream_t stream) {
    const void* xseq = d_in[0];
    detect_k<<<1, 256, 0, stream>>>((const unsigned int*)xseq);
    prep_k<<<2048, 256, 0, stream>>>(d_in[1], d_in[2], d_in[5], d_in[6], d_in[9],
                                     d_in[10], d_in[13], d_in[3], d_in[4], d_in[7],
                                     d_in[8], d_in[11], d_in[12], d_in[14], xseq);
    persist_k<<<NBLK, 512, 0, stream>>>(xseq, d_out);
}

// Round 14
// 6057.614 us; speedup vs baseline: 2.4766x; 1.0011x over previous
//
#include <hip/hip_runtime.h>

#define B_ 128
#define T_ 200
#define INF_ 175
#define INFP_ 192
#define H_ 1024
#define G4_ 4096
#define OUTF_ 175
#define BH3_ (3 * B_ * H_)
#define NCELL 192
#define NDEC 22
#define NWORK (NCELL + NDEC)
#define NBLK (NWORK + 1)
#define SP 16

typedef __bf16 bf16x8 __attribute__((ext_vector_type(8)));
typedef float f32x4 __attribute__((ext_vector_type(4)));

// ---- persistent device state ----
__device__ __attribute__((aligned(16))) __bf16 g_Wih1p[G4_ * INFP_];
__device__ __attribute__((aligned(16))) __bf16 g_Whh1[G4_ * H_];
__device__ __attribute__((aligned(16))) __bf16 g_Wih2[G4_ * H_];
__device__ __attribute__((aligned(16))) __bf16 g_Whh2[G4_ * H_];
__device__ __attribute__((aligned(16))) __bf16 g_Wih3[G4_ * H_];
__device__ __attribute__((aligned(16))) __bf16 g_Whh3[G4_ * H_];
__device__ __attribute__((aligned(16))) __bf16 g_Wdec[OUTF_ * H_];
__device__ float g_bsum[3 * G4_];
__device__ float g_bdec[OUTF_];
__device__ __attribute__((aligned(16))) __bf16 g_h[2][BH3_];
__device__ __attribute__((aligned(16))) __bf16 g_infp[B_ * INFP_];
__device__ __attribute__((aligned(16))) __bf16 g_xp[(long)T_ * B_ * INFP_]; // padded bf16 xseq
__device__ int g_isf32;
__device__ int g_flags[256 * SP];
__device__ int g_dflags[32 * SP];
__device__ int g_gen8[8 * SP];
__device__ int g_iready8[8 * SP];

__device__ __forceinline__ f32x4 mfma_bf16(bf16x8 a, bf16x8 b, f32x4 c) {
    return __builtin_amdgcn_mfma_f32_16x16x32_bf16(a, b, c, 0, 0, 0);
}
__device__ __forceinline__ bf16x8 ld8(const __bf16* p) {
    return *reinterpret_cast<const bf16x8*>(p);
}
__device__ __forceinline__ float sigm(float x) { return 1.f / (1.f + expf(-x)); }
__device__ __forceinline__ float rdf(const void* p, long i, int f32) {
    return f32 ? ((const float*)p)[i] : (float)((const __bf16*)p)[i];
}
__device__ __forceinline__ unsigned short bf2u(__bf16 v) {
    union { __bf16 b; unsigned short u; } c; c.b = v; return c.u;
}

// LDS-publish barrier that does NOT drain vmcnt: my ds ops complete
// (lgkmcnt 0), then raw s_barrier. Global prefetches stay in flight across it
// (the T3/T4 counted-vmcnt principle; __syncthreads would force vmcnt(0)).
__device__ __forceinline__ void lds_barrier() {
    asm volatile("s_waitcnt lgkmcnt(0)" ::: "memory");
    __builtin_amdgcn_s_barrier();
}

// RMW-poll at L3 coherence point + one acquire at exit. Bounded (hang-proof).
__device__ __forceinline__ void spin_rmw(int* addr, int target, int iters) {
    for (int it = 0; it < iters; ++it) {
        if (__hip_atomic_fetch_max(addr, 0, __ATOMIC_RELAXED, __HIP_MEMORY_SCOPE_AGENT) >= target)
            break;
        __builtin_amdgcn_s_sleep(1);
    }
    (void)__hip_atomic_load(addr, __ATOMIC_ACQUIRE, __HIP_MEMORY_SCOPE_AGENT);
}

// ---- dtype probe ----
__global__ void detect_k(const unsigned int* __restrict__ xw) {
    __shared__ int cnt;
    if (threadIdx.x == 0) cnt = 0;
    __syncthreads();
    unsigned int w = xw[threadIdx.x];
    int e = (w >> 7) & 0xFF;
    if (e >= 140) atomicAdd(&cnt, 1);
    __syncthreads();
    if (threadIdx.x == 0) g_isf32 = (cnt >= 16) ? 1 : 0;
}

// ---- prep ----
__global__ void prep_k(const void* Wih1, const void* Whh1, const void* Wih2,
                       const void* Whh2, const void* Wih3, const void* Whh3,
                       const void* Wdec, const void* bih1, const void* bhh1,
                       const void* bih2, const void* bhh2, const void* bih3,
                       const void* bhh3, const void* bdec, const void* xseq) {
    const int f = g_isf32;
    const int idx = blockIdx.x * 256 + threadIdx.x;
    const int stride = gridDim.x * 256;
    if (idx < 256 * SP) g_flags[idx] = 0;
    if (idx < 32 * SP) g_dflags[idx] = 0;
    if (idx < 8 * SP) { g_gen8[idx] = 0; g_iready8[idx] = 0; }
    for (int i = idx; i < G4_ * INFP_; i += stride) {
        int n = i / INFP_, k = i - n * INFP_;
        g_Wih1p[i] = (k < INF_) ? (__bf16)rdf(Wih1, (long)n * INF_ + k, f) : (__bf16)0.f;
    }
    for (int i = idx; i < G4_ * H_; i += stride) {
        g_Whh1[i] = (__bf16)rdf(Whh1, i, f);
        g_Wih2[i] = (__bf16)rdf(Wih2, i, f);
        g_Whh2[i] = (__bf16)rdf(Whh2, i, f);
        g_Wih3[i] = (__bf16)rdf(Wih3, i, f);
        g_Whh3[i] = (__bf16)rdf(Whh3, i, f);
    }
    for (int i = idx; i < OUTF_ * H_; i += stride) g_Wdec[i] = (__bf16)rdf(Wdec, i, f);
    for (int i = idx; i < G4_; i += stride) {
        g_bsum[i]           = rdf(bih1, i, f) + rdf(bhh1, i, f);
        g_bsum[G4_ + i]     = rdf(bih2, i, f) + rdf(bhh2, i, f);
        g_bsum[2 * G4_ + i] = rdf(bih3, i, f) + rdf(bhh3, i, f);
    }
    for (int i = idx; i < OUTF_; i += stride) g_bdec[i] = rdf(bdec, i, f);
    for (int i = idx; i < 2 * BH3_; i += stride) (&g_h[0][0])[i] = (__bf16)0.f;
    for (int i = idx; i < B_ * INFP_; i += stride) g_infp[i] = (__bf16)0.f;
    const long total = (long)T_ * B_ * INFP_;
    for (long i = idx; i < total; i += stride) {
        int k = (int)(i % INFP_);
        long bt = i / INFP_;
        int b = (int)(bt % B_);
        int t = (int)(bt / B_);
        g_xp[((long)t * B_ + b) * INFP_ + k] =
            (k < INF_) ? (__bf16)rdf(xseq, (long)b * (T_ * INF_) + (long)t * INF_ + k, f)
                       : (__bf16)0.f;
    }
}

// ---- worker barrier (r11, proven) ----
__device__ __forceinline__ void gridbar_w(int bid, int grp, int target) {
    __syncthreads();
    if (threadIdx.x == 0) {
        __threadfence();
        __hip_atomic_fetch_max(&g_flags[bid * SP], target, __ATOMIC_RELAXED, __HIP_MEMORY_SCOPE_AGENT);
        spin_rmw(&g_gen8[grp * SP], target, 4000);
    }
    __syncthreads();
}

// ---- persistent kernel ----
__global__ __launch_bounds__(512, 1) void persist_k(const void* __restrict__ xseq,
                                                    void* __restrict__ dout) {
    __shared__ char s_tile[2][2][16384];   // [buf][op][128 rows x 64 cols bf16] 64KB
    __shared__ float s_acc[B_ * 4 * 16];   // 32KB
    __shared__ float s_c[B_ * 16];         // 8KB
    __shared__ int s_nf, s_nd;
    const int bid = blockIdx.x;
    const int grp = bid & 7;
    const int tid = threadIdx.x;
    const int lane = tid & 63;
    const int wid = tid >> 6;
    const int rlo = lane & 15, khi = lane >> 4;
    const int f32o = g_isf32;
    const int r7l = rlo & 7;
    const int sw0 = (khi ^ r7l) * 16;
    const int sw1 = ((khi + 4) ^ r7l) * 16;

    if (bid < NCELL) {
        // ================= CELL BLOCK =================
        const int L = bid >> 6;
        const int hc0 = (bid & 63) << 4;
        const int op = wid >> 2;         // 0: x-GEMM, 1: recurrent GEMM
        const int g = wid & 3;           // gate
        const float* bs = g_bsum + L * G4_;
        const int XOFF = (L == 0) ? 13 : 0;   // L0 x-chunks run at loop idx 13..15

        const __bf16* Bm; int K;
        if (op == 0) {
            if (L == 0) { Bm = g_Wih1p; K = INFP_; }
            else        { Bm = (L == 1) ? g_Wih2 : g_Wih3; K = H_; }
        } else {
            Bm = (L == 0) ? g_Whh1 : (L == 1) ? g_Whh2 : g_Whh3; K = H_;
        }
        const __bf16* wp = Bm + (long)(g * H_ + hc0 + rlo) * K + khi * 8;
        bf16x8 wreg[32];
        if (K == INFP_) {
#pragma unroll
            for (int c = 0; c < 6; ++c) wreg[c] = ld8(wp + c * 32);
        } else {
#pragma unroll
            for (int c = 0; c < 32; ++c) wreg[c] = ld8(wp + c * 32);
        }

        const int strow = tid >> 2, stq = tid & 3, str7 = strow & 7;
        auto ldchunk = [&](const __bf16* src, int sA, int k0, bf16x8& v0, bf16x8& v1) {
            const __bf16* pr = src + (long)strow * sA + k0 + stq * 8;
            v0 = ld8(pr);
            v1 = ld8(pr + 32);
        };
        auto wrchunk = [&](char* tile, bf16x8 v0, bf16x8 v1) {
            char* pb = tile + strow * 128;
            *(bf16x8*)(pb + ((stq ^ str7) * 16)) = v0;
            *(bf16x8*)(pb + (((stq + 4) ^ str7) * 16)) = v1;
        };

        for (int i = tid; i < B_ * 16; i += 512) s_c[i] = 0.f;
        __syncthreads();

        for (int p = 0; p < T_; ++p) {
            const bool gt = ((p % 10) < 5);
            const __bf16* hin = g_h[p & 1];
            const __bf16* Apx; int sAx, nx;
            if (L == 0) {
                Apx = gt ? (g_xp + (long)p * B_ * INFP_) : g_infp;
                sAx = INFP_; nx = 3;
            } else {
                Apx = hin + (L - 1) * B_ * H_; sAx = H_; nx = 16;
            }
            const __bf16* Aph = hin + L * B_ * H_;
            const bool needwait = (L == 0) && !gt;   // dec(p-1) must have written infp

            // prologue: stage h chunk 0 (+ x chunk 0 when XOFF==0)
            bf16x8 rx0, rx1, rh0, rh1;
            ldchunk(Aph, H_, 0, rh0, rh1);
            if (XOFF == 0) ldchunk(Apx, sAx, 0, rx0, rx1);
            wrchunk(&s_tile[0][1][0], rh0, rh1);
            if (XOFF == 0) wrchunk(&s_tile[0][0][0], rx0, rx1);
            ldchunk(Aph, H_, 64, rh0, rh1);
            if (XOFF == 0) ldchunk(Apx, sAx, 64, rx0, rx1);
            lds_barrier();   // publish chunk 0; chunk-1 loads stay in flight

            f32x4 acc[8] = {};
            int buf = 0;
#pragma unroll
            for (int i = 0; i < 16; ++i) {
                // write chunk i+1 (regs loaded last iter; compiler inserts the
                // minimal vmcnt wait before the ds_write uses them)
                if (i < 15) wrchunk(&s_tile[buf ^ 1][1][0], rh0, rh1);
                {
                    int xj = i + 1 - XOFF;
                    if (xj >= 0 && xj < nx) wrchunk(&s_tile[buf ^ 1][0][0], rx0, rx1);
                }
                // L0 non-gt: wait for infp just before issuing its first x load
                if (i == 11 && needwait) {
                    if (tid == 0) spin_rmw(&g_iready8[grp * SP], p, 3000);
                    __syncthreads();
                }
                // issue loads for chunk i+2 (these survive the lds_barrier below)
                if (i < 14) ldchunk(Aph, H_, (i + 2) * 64, rh0, rh1);
                {
                    int xj = i + 2 - XOFF;
                    if (xj >= 0 && xj < nx) ldchunk(Apx, sAx, xj * 64, rx0, rx1);
                }
                // compute chunk i of my operand from LDS
                if (op == 1) {
                    const char* tb = &s_tile[buf][1][0];
#pragma unroll
                    for (int mf = 0; mf < 8; ++mf) {
                        const char* rb = tb + (mf * 16 + rlo) * 128;
                        acc[mf] = mfma_bf16(*(const bf16x8*)(rb + sw0), wreg[2 * i], acc[mf]);
                        acc[mf] = mfma_bf16(*(const bf16x8*)(rb + sw1), wreg[2 * i + 1], acc[mf]);
                    }
                } else {
                    int xj = i - XOFF;
                    if (xj >= 0 && xj < nx) {
                        const char* tb = &s_tile[buf][0][0];
#pragma unroll
                        for (int mf = 0; mf < 8; ++mf) {
                            const char* rb = tb + (mf * 16 + rlo) * 128;
                            acc[mf] = mfma_bf16(*(const bf16x8*)(rb + sw0), wreg[2 * xj], acc[mf]);
                            acc[mf] = mfma_bf16(*(const bf16x8*)(rb + sw1), wreg[2 * xj + 1], acc[mf]);
                        }
                    }
                }
                lds_barrier();   // publish chunk i+1; prefetch i+2 stays in flight
                buf ^= 1;
            }

            // operand-split reduce through LDS
            if (op == 1) {
#pragma unroll
                for (int mf = 0; mf < 8; ++mf)
#pragma unroll
                    for (int j = 0; j < 4; ++j) {
                        int r = mf * 16 + khi * 4 + j;
                        s_acc[(r * 4 + g) * 16 + rlo] = acc[mf][j];
                    }
            }
            __syncthreads();
            if (op == 0) {
#pragma unroll
                for (int mf = 0; mf < 8; ++mf)
#pragma unroll
                    for (int j = 0; j < 4; ++j) {
                        int r = mf * 16 + khi * 4 + j;
                        s_acc[(r * 4 + g) * 16 + rlo] += acc[mf][j];
                    }
            }
            __syncthreads();

            // epilogue: 8 waves x 16 rows, 4 cols/lane; h out = NT store
            {
                const int r = wid * 16 + rlo;
                const int hq = khi;
                f32x4 ga = *(const f32x4*)&s_acc[(r * 4 + 0) * 16 + hq * 4];
                f32x4 gf = *(const f32x4*)&s_acc[(r * 4 + 1) * 16 + hq * 4];
                f32x4 gg = *(const f32x4*)&s_acc[(r * 4 + 2) * 16 + hq * 4];
                f32x4 go = *(const f32x4*)&s_acc[(r * 4 + 3) * 16 + hq * 4];
                f32x4 cv = *(const f32x4*)&s_c[r * 16 + hq * 4];
                unsigned long long hbits;
                unsigned short* hp = (unsigned short*)&hbits;
#pragma unroll
                for (int e = 0; e < 4; ++e) {
                    int col = hc0 + hq * 4 + e;
                    float gi_ = ga[e] + bs[0 * H_ + col];
                    float gf_ = gf[e] + bs[1 * H_ + col];
                    float gg_ = gg[e] + bs[2 * H_ + col];
                    float go_ = go[e] + bs[3 * H_ + col];
                    float cn = sigm(gf_) * cv[e] + sigm(gi_) * tanhf(gg_);
                    cv[e] = cn;
                    hp[e] = bf2u((__bf16)(sigm(go_) * tanhf(cn)));
                }
                *(f32x4*)&s_c[r * 16 + hq * 4] = cv;
                __bf16* hdst = g_h[(p + 1) & 1] + L * B_ * H_ + r * H_ + hc0 + hq * 4;
                __builtin_nontemporal_store(hbits, (unsigned long long*)hdst);
            }
            gridbar_w(bid, grp, p + 1);
        }
    } else if (bid < NWORK) {
        // ================= DEC BLOCK =================
        const int db = bid - NCELL;
        const int ntile = db % 11, mh = db / 11;
        const int kk = wid >> 2;
        const int mw = wid & 3;
        const int col = ntile * 16 + rlo;
        const int colc = (col < OUTF_) ? col : (OUTF_ - 1);

        const __bf16* pb = g_Wdec + (long)colc * H_ + khi * 8;
        bf16x8 dw[16];
#pragma unroll
        for (int c = 0; c < 16; ++c) dw[c] = ld8(pb + (kk * 16 + c) * 32);

        const int strow = tid >> 3, stc8 = tid & 7, str7 = strow & 7;
        char* const dt0 = &s_tile[0][0][0];
        char* const dt1 = &s_tile[1][0][0];

        auto decwork = [&](int t, bool winf) {
            const bool gtn = (((t + 1) % 10) < 5);   // next step uses ground truth?
            const __bf16* h2 = g_h[(t + 1) & 1] + 2 * B_ * H_;
            const __bf16* hrow = h2 + (long)(mh * 64 + strow) * H_ + stc8 * 8;
            bf16x8 rv = ld8(hrow);
            *(bf16x8*)(dt0 + strow * 128 + ((stc8 ^ str7) * 16)) = rv;
            rv = ld8(hrow + 64);
            lds_barrier();   // publish chunk 0; chunk-1 load stays in flight
            f32x4 acc = {};
            int b = 0;
#pragma unroll
            for (int i = 0; i < 16; ++i) {
                if (i < 15) *(bf16x8*)((b ? dt0 : dt1) + strow * 128 + ((stc8 ^ str7) * 16)) = rv;
                if (i < 14) rv = ld8(hrow + (i + 2) * 64);
                {
                    const char* rb = (b ? dt1 : dt0) + (mw * 16 + rlo) * 128;
                    bf16x8 a0 = *(const bf16x8*)(rb + sw0);
                    bf16x8 a1 = *(const bf16x8*)(rb + sw1);
                    if (i < 8) {
                        if (kk == 0) {
                            acc = mfma_bf16(a0, dw[2 * i], acc);
                            acc = mfma_bf16(a1, dw[2 * i + 1], acc);
                        }
                    } else {
                        if (kk == 1) {
                            acc = mfma_bf16(a0, dw[2 * i - 16], acc);
                            acc = mfma_bf16(a1, dw[2 * i - 15], acc);
                        }
                    }
                }
                lds_barrier();
                b ^= 1;
            }
            if (kk == 1) {
#pragma unroll
                for (int j = 0; j < 4; ++j)
                    s_acc[(mw * 16 + khi * 4 + j) * 16 + rlo] = acc[j];
            }
            __syncthreads();
            if (kk == 0) {
#pragma unroll
                for (int j = 0; j < 4; ++j)
                    acc[j] += s_acc[(mw * 16 + khi * 4 + j) * 16 + rlo];
                if (col < OUTF_) {
                    const float bias = g_bdec[col];
#pragma unroll
                    for (int j = 0; j < 4; ++j) {
                        int row = mh * 64 + mw * 16 + khi * 4 + j;
                        float ov = acc[j] + bias;
                        long oidx = (long)row * (T_ * OUTF_) + (long)t * OUTF_ + col;
                        if (f32o) __builtin_nontemporal_store(ov, (float*)dout + oidx);
                        else __builtin_nontemporal_store(bf2u((__bf16)ov), (unsigned short*)dout + oidx);
                        if (winf && !gtn) {
                            __builtin_nontemporal_store(bf2u((__bf16)ov),
                                (unsigned short*)g_infp + row * INFP_ + col);
                        }
                    }
                }
            }
            __syncthreads();
            if (tid == 0) {
                __threadfence();
                __hip_atomic_fetch_max(&g_dflags[db * SP], t + 1, __ATOMIC_RELAXED, __HIP_MEMORY_SCOPE_AGENT);
            }
        };

        for (int p = 0; p < T_; ++p) {
            if (p >= 1) decwork(p - 1, true);
            gridbar_w(bid, grp, p + 1);
        }
        decwork(T_ - 1, false);
    } else {
        // ======== MASTER BLOCK (r11, proven) ========
        for (int p = 0; p < T_; ++p) {
            const int tgt = p + 1;
            bool ir_done = false;
            for (int it = 0; it < 2000; ++it) {
                if (tid == 0) { s_nf = 0; s_nd = 0; }
                __syncthreads();
                int bad_f = 0, bad_d = 0;
                if (tid < NWORK)
                    bad_f = (__hip_atomic_fetch_max(&g_flags[tid * SP], 0, __ATOMIC_RELAXED, __HIP_MEMORY_SCOPE_AGENT) < tgt);
                if (!ir_done && tid < NDEC)
                    bad_d = (__hip_atomic_fetch_max(&g_dflags[tid * SP], 0, __ATOMIC_RELAXED, __HIP_MEMORY_SCOPE_AGENT) < p);
                if (bad_f) s_nf = 1;
                if (bad_d) s_nd = 1;
                __syncthreads();
                if (!ir_done && !s_nd) {
                    if (tid < 8)
                        __hip_atomic_fetch_max(&g_iready8[tid * SP], p, __ATOMIC_RELAXED, __HIP_MEMORY_SCOPE_AGENT);
                    ir_done = true;
                }
                if (!s_nf) break;
                __builtin_amdgcn_s_sleep(1);
            }
            if (!ir_done && tid < 8)
                __hip_atomic_fetch_max(&g_iready8[tid * SP], p, __ATOMIC_RELAXED, __HIP_MEMORY_SCOPE_AGENT);
            __syncthreads();
            if (tid < 8)
                __hip_atomic_fetch_max(&g_gen8[tid * SP], tgt, __ATOMIC_RELAXED, __HIP_MEMORY_SCOPE_AGENT);
        }
    }
}

extern "C" void kernel_launch(void* const* d_in, const int* in_sizes, int n_in,
                              void* d_out, int out_size, void* d_ws, size_t ws_size,
                              hipStream_t stream) {
    const void* xseq = d_in[0];
    detect_k<<<1, 256, 0, stream>>>((const unsigned int*)xseq);
    prep_k<<<2048, 256, 0, stream>>>(d_in[1], d_in[2], d_in[5], d_in[6], d_in[9],
                                     d_in[10], d_in[13], d_in[3], d_in[4], d_in[7],
                                     d_in[8], d_in[11], d_in[12], d_in[14], xseq);
    persist_k<<<NBLK, 512, 0, stream>>>(xseq, d_out);
}